// Round 1
// baseline (2064.645 us; speedup 1.0000x reference)
//
#include <hip/hip_runtime.h>
#include <stdint.h>

#define B_DIM 8192
#define D_DIM 1024
#define H_DIM 2048
#define E_DIM 8
#define C_DIM 1024

typedef unsigned short u16;
typedef _Float16 f16x8 __attribute__((ext_vector_type(8)));
typedef float f32x4 __attribute__((ext_vector_type(4)));

__device__ __forceinline__ void store_val(float* p, float v) { *p = v; }
__device__ __forceinline__ void store_val(_Float16* p, float v) { *p = (_Float16)v; }

__device__ __forceinline__ void async_cp16(const void* g, void* l) {
  __builtin_amdgcn_global_load_lds((const __attribute__((address_space(1))) void*)g,
                                   (__attribute__((address_space(3))) void*)l, 16, 0, 0);
}

// ---------------------------------------------------------------------------
// C = act(A[M x K] * Bt[N x K]^T + bias), A/Bt fp16 row-major, out fp16 or fp32.
// M fixed by gridDim.y*128, N by gridDim.x*128. K % 64 == 0.
// 128x128 block tile, BK=64, 4 waves each computing 64x64 via 4x4 mfma tiles.
// ---------------------------------------------------------------------------
template <bool RELU, typename OUT_T>
__global__ void __launch_bounds__(256) gemm_bt(
    const _Float16* __restrict__ A, const _Float16* __restrict__ Bt,
    const float* __restrict__ bias, OUT_T* __restrict__ out,
    int K, long rs)
{
  __shared__ _Float16 ldsA[128 * 64];
  __shared__ _Float16 ldsB[128 * 64];

  const int tid  = threadIdx.x;
  const int wave = tid >> 6;
  const int lane = tid & 63;
  const int q    = lane >> 4;
  const int l16  = lane & 15;
  const int l8   = lane >> 3;
  const int l7   = lane & 7;

  const int m0   = blockIdx.y * 128;
  const int n0   = blockIdx.x * 128;
  const int wrow = (wave >> 1) * 64;
  const int wcol = (wave & 1) * 64;

  // Staging: chunk ci = wave*4+i covers storage slots [ci*64, ci*64+64).
  // Slot s=(r,j): r=s>>3 (tile row), j=s&7 (16B chunk), holds k-chunk j^(r&7).
  const int swz_st = ((l7 ^ l8) << 3);  // element offset within row of A/Bt
  const _Float16* pa[4];
  const _Float16* pb[4];
#pragma unroll
  for (int i = 0; i < 4; ++i) {
    int ci = wave * 4 + i;
    pa[i] = A  + (size_t)(m0 + ci * 8 + l8) * K + swz_st;
    pb[i] = Bt + (size_t)(n0 + ci * 8 + l8) * K + swz_st;
  }

  // LDS read byte offsets (16B aligned): row*128 + ((kchunk)^(row&7))*16
  int a_off[2][4], b_off[2][4];
#pragma unroll
  for (int kk = 0; kk < 2; ++kk) {
#pragma unroll
    for (int r = 0; r < 4; ++r) {
      int sw = ((kk * 4 + q) ^ (l16 & 7)) << 4;
      a_off[kk][r] = (wrow + r * 16 + l16) * 128 + sw;
      b_off[kk][r] = (wcol + r * 16 + l16) * 128 + sw;
    }
  }

  f32x4 acc[4][4];
#pragma unroll
  for (int r = 0; r < 4; ++r)
#pragma unroll
    for (int c = 0; c < 4; ++c)
      acc[r][c] = (f32x4){0.f, 0.f, 0.f, 0.f};

  const char* lAc = (const char*)ldsA;
  const char* lBc = (const char*)ldsB;

  for (int kt = 0; kt < K; kt += 64) {
    __syncthreads();
#pragma unroll
    for (int i = 0; i < 4; ++i) {
      int ci = wave * 4 + i;
      async_cp16(pa[i], ldsA + ci * 512);
      async_cp16(pb[i], ldsB + ci * 512);
      pa[i] += 64;
      pb[i] += 64;
    }
    __syncthreads();
#pragma unroll
    for (int kk = 0; kk < 2; ++kk) {
      f16x8 af[4], bfv[4];
#pragma unroll
      for (int r = 0; r < 4; ++r) af[r]  = *(const f16x8*)(lAc + a_off[kk][r]);
#pragma unroll
      for (int c = 0; c < 4; ++c) bfv[c] = *(const f16x8*)(lBc + b_off[kk][c]);
#pragma unroll
      for (int r = 0; r < 4; ++r)
#pragma unroll
        for (int c = 0; c < 4; ++c)
          acc[r][c] = __builtin_amdgcn_mfma_f32_16x16x32_f16(af[r], bfv[c], acc[r][c], 0, 0, 0);
    }
  }

  // Epilogue: D[row=q*4+i][col=l16] per 16x16 tile (verified C/D layout).
#pragma unroll
  for (int c = 0; c < 4; ++c) {
    int col = n0 + wcol + c * 16 + l16;
    float bv = bias[col];
#pragma unroll
    for (int r = 0; r < 4; ++r) {
      int row = m0 + wrow + r * 16 + q * 4;
      f32x4 v = acc[r][c];
#pragma unroll
      for (int i = 0; i < 4; ++i) {
        float xv = v[i] + bv;
        if (RELU) xv = fmaxf(xv, 0.f);
        store_val(out + (size_t)(row + i) * rs + col, xv);
      }
    }
  }
}

// ---------------------------------------------------------------------------
__global__ void cast_f32_f16(const float* __restrict__ in, _Float16* __restrict__ out, int n) {
  int i = (blockIdx.x * blockDim.x + threadIdx.x) * 4;
  if (i >= n) return;
  float4 v = *(const float4*)(in + i);
  union { _Float16 h[4]; uint2 u; } r;
  r.h[0] = (_Float16)v.x; r.h[1] = (_Float16)v.y;
  r.h[2] = (_Float16)v.z; r.h[3] = (_Float16)v.w;
  *(uint2*)(out + i) = r.u;
}

// in [R][Cn] fp32 (batched z) -> out [Cn][R] fp16
__global__ void transpose_cast(const float* __restrict__ in, _Float16* __restrict__ out,
                               int R, int Cn) {
  __shared__ float tile[32][33];
  size_t zb = (size_t)blockIdx.z * R * Cn;
  in  += zb;
  out += zb;
  int c0 = blockIdx.x * 32, r0 = blockIdx.y * 32;
  int tx = threadIdx.x, ty = threadIdx.y;
#pragma unroll
  for (int i = ty; i < 32; i += 8)
    tile[i][tx] = in[(size_t)(r0 + i) * Cn + c0 + tx];
  __syncthreads();
#pragma unroll
  for (int i = ty; i < 32; i += 8)
    out[(size_t)(c0 + i) * R + r0 + tx] = (_Float16)tile[tx][i];
}

// scores = softmax(g[B][D](f16) @ w2[D][8] + b2), one block per row.
__global__ void gate2_softmax(const _Float16* __restrict__ g, const float* __restrict__ w2,
                              const float* __restrict__ b2, float* __restrict__ scores) {
  int b = blockIdx.x;
  int t = threadIdx.x;            // 256
  int e = t & 7, slice = t >> 3;  // 8 experts x 32 slices
  const _Float16* gr = g + (size_t)b * D_DIM;
  float acc = 0.f;
  for (int d = slice; d < D_DIM; d += 32)
    acc += (float)gr[d] * w2[d * 8 + e];
  __shared__ float red[256];
  red[t] = acc;
  __syncthreads();
  for (int s = 16; s > 0; s >>= 1) {
    if (slice < s) red[t] += red[t + s * 8];
    __syncthreads();
  }
  __shared__ float sm[8];
  if (t < 8) sm[t] = red[t] + b2[t];
  __syncthreads();
  if (t == 0) {
    float mx = sm[0];
#pragma unroll
    for (int i = 1; i < 8; ++i) mx = fmaxf(mx, sm[i]);
    float ex[8], s = 0.f;
#pragma unroll
    for (int i = 0; i < 8; ++i) { ex[i] = expf(sm[i] - mx); s += ex[i]; }
    float inv = 1.f / s;
#pragma unroll
    for (int i = 0; i < 8; ++i) scores[(size_t)b * 8 + i] = ex[i] * inv;
  }
}

// ---------------------------------------------------------------------------
extern "C" void kernel_launch(void* const* d_in, const int* in_sizes, int n_in,
                              void* d_out, int out_size, void* d_ws, size_t ws_size,
                              hipStream_t stream) {
  const float* x   = (const float*)d_in[0];
  const float* gw1 = (const float*)d_in[1];
  const float* gb1 = (const float*)d_in[2];
  const float* gw2 = (const float*)d_in[3];
  const float* gb2 = (const float*)d_in[4];
  const float* W1  = (const float*)d_in[5];
  const float* b1  = (const float*)d_in[6];
  const float* W2  = (const float*)d_in[7];
  const float* b2  = (const float*)d_in[8];
  const float* cw  = (const float*)d_in[9];
  const float* cb  = (const float*)d_in[10];

  char* ws = (char*)d_ws;
  _Float16* xb   = (_Float16*)(ws);                       // B*D       16 MB
  _Float16* g    = (_Float16*)(ws + 16777216ull);         // B*D       16 MB
  _Float16* gw1t = (_Float16*)(ws + 33554432ull);         // D*D        2 MB
  _Float16* W1t  = (_Float16*)(ws + 35651584ull);         // E*H*D     32 MB
  _Float16* W2t  = (_Float16*)(ws + 69206016ull);         // E*H*H     64 MB
  _Float16* cwt  = (_Float16*)(ws + 136314880ull);        // C*H        4 MB
  _Float16* h    = (_Float16*)(ws + 140509184ull);        // B*H       32 MB
  _Float16* o2   = (_Float16*)(ws + 174063616ull);        // B*H       32 MB

  float* logits = (float*)d_out;
  float* scores = logits + (size_t)B_DIM * E_DIM * C_DIM;

  // fp32 -> fp16 casts / [N][K] weight transposes
  cast_f32_f16<<<B_DIM * D_DIM / 4 / 256, 256, 0, stream>>>(x, xb, B_DIM * D_DIM);
  transpose_cast<<<dim3(32, 32, 1), dim3(32, 8), 0, stream>>>(gw1, gw1t, D_DIM, D_DIM);
  transpose_cast<<<dim3(64, 32, 8), dim3(32, 8), 0, stream>>>(W1, W1t, D_DIM, H_DIM);
  transpose_cast<<<dim3(64, 64, 8), dim3(32, 8), 0, stream>>>(W2, W2t, H_DIM, H_DIM);
  transpose_cast<<<dim3(32, 64, 1), dim3(32, 8), 0, stream>>>(cw, cwt, H_DIM, C_DIM);

  // Router
  gemm_bt<true, _Float16><<<dim3(8, 64), 256, 0, stream>>>(xb, gw1t, gb1, g, D_DIM, (long)D_DIM);
  gate2_softmax<<<B_DIM, 256, 0, stream>>>(g, gw2, gb2, scores);

  // Experts: h = relu(x W1e + b1e); o2 = h W2e + b2e; logits_e = o2 clf_w + clf_b
  for (int e = 0; e < E_DIM; ++e) {
    gemm_bt<true, _Float16><<<dim3(16, 64), 256, 0, stream>>>(
        xb, W1t + (size_t)e * H_DIM * D_DIM, b1 + e * H_DIM, h, D_DIM, (long)H_DIM);
    gemm_bt<false, _Float16><<<dim3(16, 64), 256, 0, stream>>>(
        h, W2t + (size_t)e * H_DIM * H_DIM, b2 + e * H_DIM, o2, H_DIM, (long)H_DIM);
    gemm_bt<false, float><<<dim3(8, 64), 256, 0, stream>>>(
        o2, cwt, cb, logits + (size_t)e * C_DIM, H_DIM, (long)(E_DIM * C_DIM));
  }
}

// Round 2
// 1590.766 us; speedup vs baseline: 1.2979x; 1.2979x over previous
//
#include <hip/hip_runtime.h>
#include <stdint.h>

#define B_DIM 8192
#define D_DIM 1024
#define H_DIM 2048
#define E_DIM 8
#define C_DIM 1024

typedef _Float16 f16x8 __attribute__((ext_vector_type(8)));
typedef float f32x4 __attribute__((ext_vector_type(4)));

__device__ __forceinline__ void store_val(float* p, float v) { *p = v; }
__device__ __forceinline__ void store_val(_Float16* p, float v) { *p = (_Float16)v; }

__device__ __forceinline__ void async_cp16(const void* g, void* l) {
  __builtin_amdgcn_global_load_lds((const __attribute__((address_space(1))) void*)g,
                                   (__attribute__((address_space(3))) void*)l, 16, 0, 0);
}

// ---------------------------------------------------------------------------
// out = act(A[M x K] * Bt[N x K]^T + bias), A/Bt fp16 row-major, out fp16/fp32.
// Batched over blockIdx.z with element strides aZ/bZ/biasZ/outZ.
// 128x128 tile, BK=64, 4 waves x (4x4) 16x16x32 f16 MFMA tiles (m97 ladder).
// ---------------------------------------------------------------------------
template <bool RELU, bool BIAS, typename OUT_T>
__global__ void __launch_bounds__(256) gemm_bt(
    const _Float16* __restrict__ A, long aZ,
    const _Float16* __restrict__ Bt, long bZ,
    const float* __restrict__ bias, long biasZ,
    OUT_T* __restrict__ out, long outZ,
    int K, long rs)
{
  __shared__ _Float16 ldsA[128 * 64];
  __shared__ _Float16 ldsB[128 * 64];

  const int z = blockIdx.z;
  A   += (size_t)z * aZ;
  Bt  += (size_t)z * bZ;
  if (BIAS) bias += (size_t)z * biasZ;
  out += (size_t)z * outZ;

  const int tid  = threadIdx.x;
  const int wave = tid >> 6;
  const int lane = tid & 63;
  const int q    = lane >> 4;
  const int l16  = lane & 15;
  const int l8   = lane >> 3;
  const int l7   = lane & 7;

  const int m0   = blockIdx.y * 128;
  const int n0   = blockIdx.x * 128;
  const int wrow = (wave >> 1) * 64;
  const int wcol = (wave & 1) * 64;

  // Staging: chunk ci = wave*4+i covers storage slots [ci*64, ci*64+64).
  // Slot s=(r,j): r=s>>3 (tile row), j=s&7 (16B chunk), holds k-chunk j^(r&7).
  const int swz_st = ((l7 ^ l8) << 3);
  const _Float16* pa[4];
  const _Float16* pb[4];
#pragma unroll
  for (int i = 0; i < 4; ++i) {
    int ci = wave * 4 + i;
    pa[i] = A  + (size_t)(m0 + ci * 8 + l8) * K + swz_st;
    pb[i] = Bt + (size_t)(n0 + ci * 8 + l8) * K + swz_st;
  }

  // LDS read byte offsets (16B aligned): row*128B + ((kchunk)^(row&7))*16B
  int a_off[2][4], b_off[2][4];
#pragma unroll
  for (int kk = 0; kk < 2; ++kk) {
#pragma unroll
    for (int r = 0; r < 4; ++r) {
      int sw = ((kk * 4 + q) ^ (l16 & 7)) << 4;
      a_off[kk][r] = (wrow + r * 16 + l16) * 128 + sw;
      b_off[kk][r] = (wcol + r * 16 + l16) * 128 + sw;
    }
  }

  f32x4 acc[4][4];
#pragma unroll
  for (int r = 0; r < 4; ++r)
#pragma unroll
    for (int c = 0; c < 4; ++c)
      acc[r][c] = (f32x4){0.f, 0.f, 0.f, 0.f};

  const char* lAc = (const char*)ldsA;
  const char* lBc = (const char*)ldsB;

  for (int kt = 0; kt < K; kt += 64) {
    __syncthreads();
#pragma unroll
    for (int i = 0; i < 4; ++i) {
      int ci = wave * 4 + i;
      async_cp16(pa[i], ldsA + ci * 512);
      async_cp16(pb[i], ldsB + ci * 512);
      pa[i] += 64;
      pb[i] += 64;
    }
    __syncthreads();
#pragma unroll
    for (int kk = 0; kk < 2; ++kk) {
      f16x8 af[4], bfv[4];
#pragma unroll
      for (int r = 0; r < 4; ++r) af[r]  = *(const f16x8*)(lAc + a_off[kk][r]);
#pragma unroll
      for (int c = 0; c < 4; ++c) bfv[c] = *(const f16x8*)(lBc + b_off[kk][c]);
#pragma unroll
      for (int r = 0; r < 4; ++r)
#pragma unroll
        for (int c = 0; c < 4; ++c)
          acc[r][c] = __builtin_amdgcn_mfma_f32_16x16x32_f16(af[r], bfv[c], acc[r][c], 0, 0, 0);
    }
  }

  // Epilogue: D[row=q*4+i][col=l16] per 16x16 tile (verified C/D layout).
#pragma unroll
  for (int c = 0; c < 4; ++c) {
    int col = n0 + wcol + c * 16 + l16;
    float bv = BIAS ? bias[col] : 0.f;
#pragma unroll
    for (int r = 0; r < 4; ++r) {
      int row = m0 + wrow + r * 16 + q * 4;
      f32x4 v = acc[r][c];
#pragma unroll
      for (int i = 0; i < 4; ++i) {
        float xv = v[i] + bv;
        if (RELU) xv = fmaxf(xv, 0.f);
        store_val(out + (size_t)(row + i) * rs + col, xv);
      }
    }
  }
}

// ---------------------------------------------------------------------------
__global__ void cast_f32_f16(const float* __restrict__ in, _Float16* __restrict__ out, int n) {
  int i = (blockIdx.x * blockDim.x + threadIdx.x) * 4;
  if (i >= n) return;
  float4 v = *(const float4*)(in + i);
  union { _Float16 h[4]; uint2 u; } r;
  r.h[0] = (_Float16)v.x; r.h[1] = (_Float16)v.y;
  r.h[2] = (_Float16)v.z; r.h[3] = (_Float16)v.w;
  *(uint2*)(out + i) = r.u;
}

// in [R][Cn] fp32 (batched over z) -> out [Cn][R] fp16
__global__ void transpose_cast(const float* __restrict__ in, _Float16* __restrict__ out,
                               int R, int Cn) {
  __shared__ float tile[32][33];
  in  += (size_t)blockIdx.z * R * Cn;
  out += (size_t)blockIdx.z * R * Cn;
  int c0 = blockIdx.x * 32, r0 = blockIdx.y * 32;
  int tx = threadIdx.x, ty = threadIdx.y;
#pragma unroll
  for (int i = ty; i < 32; i += 8)
    tile[i][tx] = in[(size_t)(r0 + i) * Cn + c0 + tx];
  __syncthreads();
#pragma unroll
  for (int i = ty; i < 32; i += 8)
    out[(size_t)(c0 + i) * R + r0 + tx] = (_Float16)tile[tx][i];
}

// scores = softmax(g[B][D](f16) @ w2[D][8] + b2), one block per row.
__global__ void gate2_softmax(const _Float16* __restrict__ g, const float* __restrict__ w2,
                              const float* __restrict__ b2, float* __restrict__ scores) {
  int b = blockIdx.x;
  int t = threadIdx.x;            // 256
  int e = t & 7, slice = t >> 3;  // 8 experts x 32 slices
  const _Float16* gr = g + (size_t)b * D_DIM;
  float acc = 0.f;
  for (int d = slice; d < D_DIM; d += 32)
    acc += (float)gr[d] * w2[d * 8 + e];
  __shared__ float red[256];
  red[t] = acc;
  __syncthreads();
  for (int s = 16; s > 0; s >>= 1) {
    if (slice < s) red[t] += red[t + s * 8];
    __syncthreads();
  }
  __shared__ float sm[8];
  if (t < 8) sm[t] = red[t] + b2[t];
  __syncthreads();
  if (t == 0) {
    float mx = sm[0];
#pragma unroll
    for (int i = 1; i < 8; ++i) mx = fmaxf(mx, sm[i]);
    float ex[8], s = 0.f;
#pragma unroll
    for (int i = 0; i < 8; ++i) { ex[i] = expf(sm[i] - mx); s += ex[i]; }
    float inv = 1.f / s;
#pragma unroll
    for (int i = 0; i < 8; ++i) scores[(size_t)b * 8 + i] = ex[i] * inv;
  }
}

// bc[e][c] = cb[c] + sum_k b2[e][k] * cw[k][c]   (combined classifier bias)
__global__ void combined_bias(const float* __restrict__ b2, const float* __restrict__ cw,
                              const float* __restrict__ cb, float* __restrict__ bc) {
  int e  = blockIdx.y;
  int cl = threadIdx.x & 63;
  int c  = blockIdx.x * 64 + cl;
  int ks = threadIdx.x >> 6;  // 4 k-slices
  float acc = 0.f;
  for (int k = ks; k < H_DIM; k += 4)
    acc += b2[e * H_DIM + k] * cw[(size_t)k * C_DIM + c];
  __shared__ float red[256];
  red[threadIdx.x] = acc;
  __syncthreads();
  if (ks == 0)
    bc[(size_t)e * C_DIM + c] = red[cl] + red[cl + 64] + red[cl + 128] + red[cl + 192] + cb[c];
}

// ---------------------------------------------------------------------------
extern "C" void kernel_launch(void* const* d_in, const int* in_sizes, int n_in,
                              void* d_out, int out_size, void* d_ws, size_t ws_size,
                              hipStream_t stream) {
  const float* x   = (const float*)d_in[0];
  const float* gw1 = (const float*)d_in[1];
  const float* gb1 = (const float*)d_in[2];
  const float* gw2 = (const float*)d_in[3];
  const float* gb2 = (const float*)d_in[4];
  const float* W1  = (const float*)d_in[5];
  const float* b1  = (const float*)d_in[6];
  const float* W2  = (const float*)d_in[7];
  const float* b2  = (const float*)d_in[8];
  const float* cw  = (const float*)d_in[9];
  const float* cb  = (const float*)d_in[10];

  char* ws = (char*)d_ws;
  _Float16* xb     = (_Float16*)(ws);                    // B*D        16 MB
  _Float16* g      = (_Float16*)(ws + 16777216ull);      // B*D        16 MB
  _Float16* gw1t   = (_Float16*)(ws + 33554432ull);      // D*D         2 MB
  _Float16* W1t    = (_Float16*)(ws + 35651584ull);      // E*H*D      32 MB
  _Float16* W2c    = (_Float16*)(ws + 69206016ull);      // E*H*H      64 MB (cast, NOT transposed)
  _Float16* cwt    = (_Float16*)(ws + 136314880ull);     // C*H         4 MB
  _Float16* WcombT = (_Float16*)(ws + 140509184ull);     // E*C*H      32 MB
  float*    bc     = (float*)   (ws + 174063616ull);     // E*C        32 KB
  _Float16* h_all  = (_Float16*)(ws + 174096384ull);     // E*B*H     256 MB
                                                         // total ~422 MB

  float* logits = (float*)d_out;
  float* scores = logits + (size_t)B_DIM * E_DIM * C_DIM;

  // Precision prep: casts + [N][K] weight transposes
  cast_f32_f16<<<B_DIM * D_DIM / 4 / 256, 256, 0, stream>>>(x, xb, B_DIM * D_DIM);
  transpose_cast<<<dim3(32, 32, 1), dim3(32, 8), 0, stream>>>(gw1, gw1t, D_DIM, D_DIM);
  transpose_cast<<<dim3(64, 32, 8), dim3(32, 8), 0, stream>>>(W1, W1t, D_DIM, H_DIM);
  cast_f32_f16<<<E_DIM * H_DIM * H_DIM / 4 / 256, 256, 0, stream>>>(W2, W2c, E_DIM * H_DIM * H_DIM);
  transpose_cast<<<dim3(32, 64, 1), dim3(32, 8), 0, stream>>>(cw, cwt, H_DIM, C_DIM);

  // Router
  gemm_bt<true, true, _Float16><<<dim3(8, 64, 1), 256, 0, stream>>>(
      xb, 0, gw1t, 0, gb1, 0, g, 0, D_DIM, (long)D_DIM);
  gate2_softmax<<<B_DIM, 256, 0, stream>>>(g, gw2, gb2, scores);

  // Classifier folding: WcombT[e][c][h'] = sum_k2 Wc[k2][c] * W2[e][h'][k2]
  //   A = cwt [C][k2], Bt = W2c[e] [h'][k2]  (M=C, N=H, K=H)
  gemm_bt<false, false, _Float16><<<dim3(16, 8, 8), 256, 0, stream>>>(
      cwt, 0, W2c, (long)H_DIM * H_DIM, nullptr, 0,
      WcombT, (long)C_DIM * H_DIM, H_DIM, (long)H_DIM);
  combined_bias<<<dim3(C_DIM / 64, E_DIM), 256, 0, stream>>>(b2, cw, cb, bc);

  // Layer 1, all experts batched: h_all[e] = relu(x @ W1[e] + b1[e])
  gemm_bt<true, true, _Float16><<<dim3(16, 64, 8), 256, 0, stream>>>(
      xb, 0, W1t, (long)H_DIM * D_DIM, b1, (long)H_DIM,
      h_all, (long)B_DIM * H_DIM, D_DIM, (long)H_DIM);

  // Fused layer2+classifier, all experts: logits[:,e,:] = h_all[e] @ Wcomb[e] + bc[e]
  gemm_bt<false, true, float><<<dim3(8, 64, 8), 256, 0, stream>>>(
      h_all, (long)B_DIM * H_DIM, WcombT, (long)C_DIM * H_DIM, bc, (long)C_DIM,
      logits, (long)C_DIM, H_DIM, (long)(E_DIM * C_DIM));
}